// Round 2
// baseline (228.712 us; speedup 1.0000x reference)
//
#include <hip/hip_runtime.h>

// RandomForest "mean of E linear heads" == single linear head with averaged
// weights:  out[i] = x[i,:] . mean_e(W[e,0,:]) + mean_e(b[e]).
//
// Dtypes: fp32 in / fp32 out, per the reference and the harness contract.
// (Round-1 post-mortem: treating fp32 inputs as bf16 produced NaNs — random
// fp32 mantissa bits read as bf16 exponent 0xFF. Inputs are definitely fp32.)
//
// Streaming kernel: 160 MB x-read + 16 MB out-write => ~28 us HBM floor.

#define BLOCK 256
#define RPT 4  // rows per thread

__global__ __launch_bounds__(BLOCK) void rf_mean_linear(
    const float* __restrict__ x,     // [batch, 10] fp32
    const float* __restrict__ W,     // [10, 1, 10] fp32
    const float* __restrict__ bias,  // [10, 1] fp32
    float* __restrict__ out,         // [batch, 1] fp32
    int batch)
{
    __shared__ float s_w[10];
    __shared__ float s_b;

    // Average the 10 per-estimator weight rows (tiny: 100 floats, cached).
    if (threadIdx.x < 10) {
        float acc = 0.f;
        #pragma unroll
        for (int e = 0; e < 10; ++e) acc += W[e * 10 + threadIdx.x];
        s_w[threadIdx.x] = acc * 0.1f;
    }
    if (threadIdx.x == 0) {
        float acc = 0.f;
        #pragma unroll
        for (int e = 0; e < 10; ++e) acc += bias[e];
        s_b = acc * 0.1f;
    }
    __syncthreads();

    float w[10];
    #pragma unroll
    for (int j = 0; j < 10; ++j) w[j] = s_w[j];
    const float bavg = s_b;

    const long long base =
        ((long long)blockIdx.x * BLOCK + threadIdx.x) * RPT;
    if (base >= batch) return;  // batch % 4 == 0, no partial groups

    // 4 rows = 40 floats = 160 B = 10 x float4; 160*i is 16B-aligned.
    const float4* p = (const float4*)(x + base * 10);
    float4 d[10];
    #pragma unroll
    for (int q = 0; q < 10; ++q) d[q] = p[q];
    const float* f = (const float*)d;

    float r[RPT];
    #pragma unroll
    for (int rr = 0; rr < RPT; ++rr) {
        float acc = bavg;
        #pragma unroll
        for (int j = 0; j < 10; ++j)
            acc = fmaf(f[rr * 10 + j], w[j], acc);
        r[rr] = acc;
    }

    float4 res;
    res.x = r[0]; res.y = r[1]; res.z = r[2]; res.w = r[3];
    *(float4*)(out + base) = res;  // 16 B store, aligned (base % 4 == 0)
}

extern "C" void kernel_launch(void* const* d_in, const int* in_sizes, int n_in,
                              void* d_out, int out_size, void* d_ws, size_t ws_size,
                              hipStream_t stream) {
    const float* x   = (const float*)d_in[0];
    const float* W   = (const float*)d_in[1];
    const float* b   = (const float*)d_in[2];
    float* out = (float*)d_out;

    const int batch = out_size;  // 4,000,000
    const int groups = (batch + RPT - 1) / RPT;
    const int blocks = (groups + BLOCK - 1) / BLOCK;
    rf_mean_linear<<<blocks, BLOCK, 0, stream>>>(x, W, b, out, batch);
}

// Round 3
// 226.435 us; speedup vs baseline: 1.0101x; 1.0101x over previous
//
#include <hip/hip_runtime.h>

// RandomForest "mean of E linear heads" == single linear head with averaged
// weights:  out[i] = x[i,:] . mean_e(W[e,0,:]) + mean_e(b[e]).   fp32 in/out.
//
// R2 post-mortem: kernel passed but per-instruction access was strided
// (lane stride 160 B -> 64 line-requests/instr). This version stages through
// LDS: perfectly coalesced global float4 loads, conflict-free b128 LDS
// reads (bank start (20t)%32 covers all 8 groups evenly), 2 rows/thread.
//
// Block = 320 thr (5 waves), 640 rows/block, 6250 blocks -> no tail
// (6250 * 640 == 4,000,000). LDS = 25.6 KB -> 6 blocks/CU.
// HBM: 160 MB read + 16 MB write => ~28 us floor at 6.3 TB/s.

#define BLOCK 320
#define ROWS_PER_BLOCK 640           // 2 rows per thread
#define F4_PER_BLOCK (ROWS_PER_BLOCK * 10 / 4)   // 1600
#define F4_PER_THREAD (F4_PER_BLOCK / BLOCK)     // 5

__global__ __launch_bounds__(BLOCK) void rf_mean_linear(
    const float* __restrict__ x,     // [batch, 10]
    const float* __restrict__ W,     // [10, 1, 10]
    const float* __restrict__ bias,  // [10, 1]
    float* __restrict__ out,         // [batch, 1]
    int batch)
{
    __shared__ float4 s_x[F4_PER_BLOCK];   // 25600 B, block's 640 rows row-major
    __shared__ float s_w[10];
    __shared__ float s_b;

    const int t = threadIdx.x;

    if (t < 10) {
        float acc = 0.f;
        #pragma unroll
        for (int e = 0; e < 10; ++e) acc += W[e * 10 + t];
        s_w[t] = acc * 0.1f;
    }
    if (t == 0) {
        float acc = 0.f;
        #pragma unroll
        for (int e = 0; e < 10; ++e) acc += bias[e];
        s_b = acc * 0.1f;
    }

    // Stage: 5 coalesced float4 loads per thread (1 KB per wave-instr).
    const float4* xf4 = (const float4*)x;
    const long long blk_f4 = (long long)blockIdx.x * F4_PER_BLOCK;
    #pragma unroll
    for (int k = 0; k < F4_PER_THREAD; ++k) {
        const int slot = k * BLOCK + t;
        s_x[slot] = xf4[blk_f4 + slot];
    }
    __syncthreads();

    const float bavg = s_b;
    float w[10];
    #pragma unroll
    for (int j = 0; j < 10; ++j) w[j] = s_w[j];

    // Each thread: 2 rows = 80 B contiguous LDS = 5 x ds_read_b128.
    // Bank start (20t + 4q) % 32 -> all 8 four-bank groups hit evenly
    // (8 accesses/bank = inherent b128 minimum, no excess conflict).
    float4 d[5];
    #pragma unroll
    for (int q = 0; q < 5; ++q) d[q] = s_x[t * 5 + q];
    const float* f = (const float*)d;

    float r0 = bavg, r1 = bavg;
    #pragma unroll
    for (int j = 0; j < 10; ++j) r0 = fmaf(f[j],      w[j], r0);
    #pragma unroll
    for (int j = 0; j < 10; ++j) r1 = fmaf(f[10 + j], w[j], r1);

    // Coalesced 8 B store: rows (block*640 + 2t, +1).
    const long long row = (long long)blockIdx.x * ROWS_PER_BLOCK + 2 * t;
    float2 res; res.x = r0; res.y = r1;
    *(float2*)(out + row) = res;
}

extern "C" void kernel_launch(void* const* d_in, const int* in_sizes, int n_in,
                              void* d_out, int out_size, void* d_ws, size_t ws_size,
                              hipStream_t stream) {
    const float* x   = (const float*)d_in[0];
    const float* W   = (const float*)d_in[1];
    const float* b   = (const float*)d_in[2];
    float* out = (float*)d_out;

    const int batch = in_sizes[0] / 10;               // 4,000,000
    const int blocks = batch / ROWS_PER_BLOCK;        // 6250, exact
    rf_mean_linear<<<blocks, BLOCK, 0, stream>>>(x, W, b, out, batch);
}